// Round 1
// 1128.622 us; speedup vs baseline: 1.0066x; 1.0066x over previous
//
#include <hip/hip_runtime.h>
#include <cstdint>
#include <cstddef>

// ---------------------------------------------------------------------------
// Fused GQA attention block for MI355X (gfx950).
// B=4 T=1024 D=4096 N=32 Kh=8 G=4 H=128, rotary=80, theta=1e6, eps=1e-6.
// Pipeline: [transpose+cvt weights/x -> bf16] -> GEMM(qkv) -> norm/rope/gate
//           + V transpose -> flash attention (causal) -> GEMM(out proj).
// R2 change: both GEMMs ported from the 128^2 2-barrier structure (m97-class,
// measured 881 TF = its ~900 TF ceiling) to a 256^2 8-wave deep-pipelined
// schedule: BK=32, 4-deep LDS tile ring, counted s_waitcnt vmcnt(8) (never 0
// in the main loop), per-phase {ds_read || global_load_lds -> barrier ->
// lgkmcnt(0) -> setprio(1) 16xMFMA setprio(0) -> barrier}, XOR swizzle kept.
// vmcnt discipline is provable: tile T+3 staged during tile T; boundary
// vmcnt(8) (= tiles T+2,T+3 in flight) sits BEFORE the phase-closing barrier,
// and per-phase lgkmcnt(0) drains all ds_reads before each second barrier, so
// buffer overwrite (ring slot reused 4 tiles later) can never race a read.
// MFMA layouts (guide-verified, 16x16x32 bf16):
//   A-frag: A[m=lane&15][k=(lane>>4)*8+j]
//   B-frag: B[k=(lane>>4)*8+j][n=lane&15]  (from B^T rows)
//   C/D   : row=(lane>>4)*4+r, col=lane&15
// ---------------------------------------------------------------------------

typedef __attribute__((ext_vector_type(8))) short short8;
typedef __attribute__((ext_vector_type(4))) float float4v;

__device__ __forceinline__ unsigned short f2bf(float f) {
  unsigned u = __builtin_bit_cast(unsigned, f);
  u += 0x7fffu + ((u >> 16) & 1u);            // RNE
  return (unsigned short)(u >> 16);
}
__device__ __forceinline__ float bf2f(unsigned short h) {
  unsigned u = ((unsigned)h) << 16;
  return __builtin_bit_cast(float, u);
}

// async global->LDS, 16B per lane. LDS dest is wave-uniform base + lane*16.
__device__ __forceinline__ void gload_lds16(const void* g, void* l) {
  typedef const __attribute__((address_space(1))) void as1_cv;
  typedef __attribute__((address_space(3))) void as3_v;
  __builtin_amdgcn_global_load_lds((as1_cv*)g, (as3_v*)l, 16, 0, 0);
}

// ---------------------------------------------------------------------------
// Transpose + f32->bf16 convert: dst[c][r] = bf16(src[r][c]); src is (R, C).
// ---------------------------------------------------------------------------
__global__ __launch_bounds__(256) void transpose_cvt(
    const float* __restrict__ src, unsigned short* __restrict__ dst,
    int R, int C) {
  __shared__ float tile[32][33];
  const int c0 = blockIdx.x * 32, r0 = blockIdx.y * 32;
  for (int i = threadIdx.y; i < 32; i += 8)
    tile[i][threadIdx.x] = src[(size_t)(r0 + i) * C + c0 + threadIdx.x];
  __syncthreads();
  for (int i = threadIdx.y; i < 32; i += 8)
    dst[(size_t)(c0 + i) * R + r0 + threadIdx.x] = f2bf(tile[threadIdx.x][i]);
}

__global__ __launch_bounds__(256) void cvt_f32_bf16(
    const float* __restrict__ src, unsigned short* __restrict__ dst, int n4) {
  int i = blockIdx.x * blockDim.x + threadIdx.x;
  if (i >= n4) return;
  float4 f = ((const float4*)src)[i];
  ushort4 o;
  o.x = f2bf(f.x); o.y = f2bf(f.y); o.z = f2bf(f.z); o.w = f2bf(f.w);
  ((ushort4*)dst)[i] = o;
}

// bf16 64x64-tile transpose for V: qkv cols [9216+kh*128, +128) -> vt (b,kh,h,t).
// grid (16 t-tiles, 2 h-tiles, 32 b*kh), block 256.
__global__ __launch_bounds__(256) void v_transpose(
    const unsigned short* __restrict__ qkv, unsigned short* __restrict__ vtb) {
  __shared__ unsigned short tile[64][65];
  const int t0 = blockIdx.x * 64, h0 = blockIdx.y * 64;
  const int bk = blockIdx.z, b = bk >> 3, kh = bk & 7;
  const int tx = threadIdx.x & 63, ty = threadIdx.x >> 6;
  const unsigned short* src =
      qkv + (size_t)(b * 1024 + t0) * 10240 + 9216 + kh * 128 + h0;
  for (int i = ty; i < 64; i += 4)
    tile[i][tx] = src[(size_t)i * 10240 + tx];
  __syncthreads();
  unsigned short* dst = vtb + ((size_t)bk * 128 + h0) * 1024 + t0;
  for (int i = ty; i < 64; i += 4)
    dst[(size_t)i * 1024 + tx] = tile[tx][i];
}

// ---------------------------------------------------------------------------
// GEMM: C(M,N) = A(M,Kd) * BT(N,Kd)^T, bf16 in, f32 acc.
// 256x256 tile, BK=32, 512 threads = 8 waves (2x4), per-wave C = 128x64.
// LDS: 4-deep ring of (A 256x32 + B 256x32) bf16 = 128 KiB.
// Rows are 64 B = 4 chunks of 16 B; physical chunk c holds global chunk
// c ^ (row & 3)  (inverse-swizzled global source + swizzled ds_read — the
// both-sides rule; pattern is perfectly 8-words/bank balanced for b128).
// Pipeline: stage tile T+3 during tile T (1 A-half + 1 B-half issue per
// phase); boundary s_waitcnt vmcnt(8) before the last barrier of each tile.
// ---------------------------------------------------------------------------
template <bool BF16OUT>
__global__ __launch_bounds__(512, 2) void gemm_bt256(
    const unsigned short* __restrict__ A, const unsigned short* __restrict__ BT,
    void* __restrict__ Cv, int M, int N, int Kd) {
  __shared__ unsigned short As[4][256 * 32];
  __shared__ unsigned short Bs[4][256 * 32];

  const int tid = threadIdx.x;
  const int lane = tid & 63;
  const int wv = tid >> 6;
  const int wr = wv >> 2, wc = wv & 3;       // 2 x 4 wave grid
  const int m0 = blockIdx.y * 256, n0 = blockIdx.x * 256;
  const int ml = lane & 15, q = lane >> 4;

  // staging addressing: half s covers rows s*128..s*128+127 of the tile.
  // lane slot: row = tid>>2, physical chunk = tid&3; source chunk = phys^row&3
  const int sr = tid >> 2;
  const int pc = tid & 3;
  const int gc = (pc ^ (sr & 3)) * 8;        // swizzled source col (ushorts)
  const unsigned short* gA0 = A + (size_t)(m0 + sr) * Kd + gc;
  const unsigned short* gB0 = BT + (size_t)(n0 + sr) * Kd + gc;
  const unsigned short* gA1 = gA0 + (size_t)128 * Kd;
  const unsigned short* gB1 = gB0 + (size_t)128 * Kd;
  const int lo0 = tid * 8;                   // LDS ushort offset, half 0
  const int lo1 = 4096 + tid * 8;            // half 1

  // fragment read addressing (row&3 == ml&3 since frag row bases are %16==0)
  const int rdc = (q ^ (ml & 3)) * 8;        // swizzled chunk for ds_read
  const int aOff = (wr * 128 + ml) * 32 + rdc;
  const int bOff = (wc * 64 + ml) * 32 + rdc;

  float4v acc[8][4];
#pragma unroll
  for (int i = 0; i < 8; ++i)
#pragma unroll
    for (int j = 0; j < 4; ++j) acc[i][j] = (float4v)0.0f;

  const int NT = Kd >> 5;                    // K tiles of 32

  // prologue: stage tiles 0..2 (12 loads per wave); wait tile 0 (oldest 4).
#pragma unroll
  for (int t = 0; t < 3; ++t) {
    gload_lds16(gA0 + t * 32, &As[t][lo0]);
    gload_lds16(gA1 + t * 32, &As[t][lo1]);
    gload_lds16(gB0 + t * 32, &Bs[t][lo0]);
    gload_lds16(gB1 + t * 32, &Bs[t][lo1]);
  }
  asm volatile("s_waitcnt vmcnt(8)" ::: "memory");
  __builtin_amdgcn_s_barrier();

  for (int T = 0; T < NT; ++T) {
    const int buf = T & 3;
    const bool doStage = (T + 3 < NT);
    const int sb = (T + 3) & 3;
    const int gk = (T + 3) * 32;

    // ---- phase 0: B frags (all 4 n) + A frags 0..3 ----
    short8 bfr[4], af[4];
#pragma unroll
    for (int j = 0; j < 4; ++j)
      bfr[j] = *(const short8*)&Bs[buf][bOff + j * 512];
#pragma unroll
    for (int i = 0; i < 4; ++i)
      af[i] = *(const short8*)&As[buf][aOff + i * 512];
    if (doStage) {
      gload_lds16(gA0 + gk, &As[sb][lo0]);
      gload_lds16(gB0 + gk, &Bs[sb][lo0]);
    }
    __builtin_amdgcn_s_barrier();
    asm volatile("s_waitcnt lgkmcnt(0)" ::: "memory");
    __builtin_amdgcn_sched_barrier(0);
    __builtin_amdgcn_s_setprio(1);
#pragma unroll
    for (int i = 0; i < 4; ++i)
#pragma unroll
      for (int j = 0; j < 4; ++j)
        acc[i][j] = __builtin_amdgcn_mfma_f32_16x16x32_bf16(af[i], bfr[j], acc[i][j], 0, 0, 0);
    __builtin_amdgcn_s_setprio(0);
    __builtin_amdgcn_s_barrier();

    // ---- phase 1: A frags 4..7 (B frags reused) ----
#pragma unroll
    for (int i = 0; i < 4; ++i)
      af[i] = *(const short8*)&As[buf][aOff + 2048 + i * 512];
    if (doStage) {
      gload_lds16(gA1 + gk, &As[sb][lo1]);
      gload_lds16(gB1 + gk, &Bs[sb][lo1]);
    }
    __builtin_amdgcn_s_barrier();
    asm volatile("s_waitcnt lgkmcnt(0)" ::: "memory");
    __builtin_amdgcn_sched_barrier(0);
    __builtin_amdgcn_s_setprio(1);
#pragma unroll
    for (int i = 0; i < 4; ++i)
#pragma unroll
      for (int j = 0; j < 4; ++j)
        acc[4 + i][j] = __builtin_amdgcn_mfma_f32_16x16x32_bf16(af[i], bfr[j], acc[4 + i][j], 0, 0, 0);
    __builtin_amdgcn_s_setprio(0);
    // boundary wait BEFORE the closing barrier: tile T+1 must be resident;
    // tiles T+2 (4 loads) and T+3 (4 loads) may stay in flight.
    if (T + 3 < NT)
      asm volatile("s_waitcnt vmcnt(8)" ::: "memory");
    else if (T + 2 < NT)
      asm volatile("s_waitcnt vmcnt(4)" ::: "memory");
    else if (T + 1 < NT)
      asm volatile("s_waitcnt vmcnt(0)" ::: "memory");
    __builtin_amdgcn_s_barrier();
  }

  // epilogue
#pragma unroll
  for (int i = 0; i < 8; ++i) {
#pragma unroll
    for (int j = 0; j < 4; ++j) {
      const int grow = m0 + wr * 128 + i * 16 + q * 4;
      const int gcol = n0 + wc * 64 + j * 16 + ml;
#pragma unroll
      for (int r = 0; r < 4; ++r) {
        size_t idx = (size_t)(grow + r) * N + gcol;
        if constexpr (BF16OUT)
          ((unsigned short*)Cv)[idx] = f2bf(acc[i][j][r]);
        else
          ((float*)Cv)[idx] = acc[i][j][r];
      }
    }
  }
}

// ---------------------------------------------------------------------------
// Postprocess q/gate/k (V handled by v_transpose):
//   hs<32 : q head hs  -> rmsnorm, rope -> q_rot; gate -> sigmoid -> sgb
//   hs>=32: k head     -> rmsnorm, rope -> k_rot  (layout (b,kh,t,h))
// One wave per (row m, slot hs in 0..39). grid 40960, block 256.
// ---------------------------------------------------------------------------
__global__ __launch_bounds__(256) void postproc_kernel(
    const unsigned short* __restrict__ qkv, const int* __restrict__ positions,
    const float* __restrict__ qnw, const float* __restrict__ knw,
    unsigned short* __restrict__ q_rot, unsigned short* __restrict__ sgb,
    unsigned short* __restrict__ k_rot) {
  const int wave = threadIdx.x >> 6, lane = threadIdx.x & 63;
  const int gslot = blockIdx.x * 4 + wave;
  const int m = gslot / 40, hs = gslot % 40;
  const int b = m >> 10, t = m & 1023;

  const unsigned short* base = (hs < 32)
      ? qkv + (size_t)m * 10240 + hs * 256
      : qkv + (size_t)m * 10240 + 8192 + (hs - 32) * 128;

  float v1 = bf2f(base[lane]);        // h = lane
  float v2 = bf2f(base[64 + lane]);   // h = lane + 64

  // RMS norm over 128 (1+w applied before rope; rope mixes channels)
  float ss = v1 * v1 + v2 * v2;
  for (int off = 32; off > 0; off >>= 1) ss += __shfl_xor(ss, off);
  const float r = rsqrtf(ss * (1.0f / 128.0f) + 1e-6f);
  const float* nw = (hs < 32) ? qnw : knw;
  v1 *= r * (1.0f + nw[lane]);
  v2 *= r * (1.0f + nw[64 + lane]);

  // RoPE dims 0..79: pair (i, i+40). ln(1e6)/40 = 0.34538776...
  const float pos = (float)positions[m];
  const int i1 = (lane < 40) ? lane : lane - 40;
  const float ang1 = pos * expf(-0.3453877639491068f * (float)i1);
  const float s1 = sinf(ang1), c1 = cosf(ang1);
  const float ang2 = pos * expf(-0.3453877639491068f * (float)(lane + 24));
  const float s2 = sinf(ang2), c2 = cosf(ang2);

  const float shA1 = __shfl(v1, (lane + 40) & 63);
  const float shA2 = __shfl(v2, (lane + 40) & 63);
  const float shX = __shfl(v1, (lane + 24) & 63);
  const float pA = (lane < 24) ? shA1 : shA2;  // x[lane+40]
  const float o1 = (lane < 40) ? (v1 * c1 - pA * s1) : (v1 * c1 + shX * s1);
  const float o2 = (lane < 16) ? (v2 * c2 + shX * s2) : v2;

  if (hs < 32) {
    size_t qb = ((size_t)m * 32 + hs) * 128;
    q_rot[qb + lane] = f2bf(o1);
    q_rot[qb + 64 + lane] = f2bf(o2);
    float g1 = bf2f(base[128 + lane]), g2 = bf2f(base[192 + lane]);
    sgb[qb + lane] = f2bf(1.0f / (1.0f + expf(-g1)));
    sgb[qb + 64 + lane] = f2bf(1.0f / (1.0f + expf(-g2)));
  } else {
    const int kh = hs - 32;
    size_t kb = ((size_t)(b * 8 + kh) * 1024 + t) * 128;
    k_rot[kb + lane] = f2bf(o1);
    k_rot[kb + 64 + lane] = f2bf(o2);
  }
}

// ---------------------------------------------------------------------------
// Flash attention. Block = (b, n, 64-row Q tile). 4 waves x 16 q-rows.
// Ks/Vts XOR-swizzled; Ps padded to stride 72. LDS = 16K+16K+9K = 41KB.
// ---------------------------------------------------------------------------
__global__ __launch_bounds__(256) void attn_kernel(
    const unsigned short* __restrict__ q_rot, const unsigned short* __restrict__ k_rot,
    const unsigned short* __restrict__ vt, const unsigned short* __restrict__ sgate,
    unsigned short* __restrict__ attn_out) {
  __shared__ unsigned short Ks[64 * 128];   // 16 chunks/row, swizzle mask 15
  __shared__ unsigned short Vts[128 * 64];  // 8 chunks/row, swizzle mask 7
  __shared__ unsigned short Ps[64 * 72];    // padded, plain stores

  const int tid = threadIdx.x;
  const int lane = tid & 63, w = tid >> 6;
  const int qt = blockIdx.x & 15;
  const int n = (blockIdx.x >> 4) & 31;
  const int b = blockIdx.x >> 9;
  const int kh = n >> 2;
  const int t0 = qt * 64;
  const int ml = lane & 15, q = lane >> 4;
  const float SCALE = 0.08838834764831845f;  // H^-0.5

  short8 aq[4];
  {
    const unsigned short* qp =
        q_rot + (((size_t)(b * 1024 + t0 + w * 16 + ml)) * 32 + n) * 128 + q * 8;
#pragma unroll
    for (int ks = 0; ks < 4; ++ks) aq[ks] = *(const short8*)(qp + ks * 32);
  }

  float4v O[8];
#pragma unroll
  for (int i = 0; i < 8; ++i) O[i] = (float4v)0.0f;
  float mrow[4] = {-3e38f, -3e38f, -3e38f, -3e38f};
  float lrow[4] = {0.f, 0.f, 0.f, 0.f};

  const unsigned short* kbase = k_rot + (size_t)(b * 8 + kh) * 1024 * 128;
  const unsigned short* vbase = vt + (size_t)(b * 8 + kh) * 128 * 1024;
  const int rK = tid >> 4, cK = tid & 15;  // K stage: 64 rows x 16 chunks
  const int cKsw = (cK ^ rK) * 8;          // rK&15 == rK
  const int rV = tid >> 3, cV = tid & 7;   // V stage: 128 rows x 8 chunks
  const int cVsw = (cV ^ (rV & 7)) * 8;

  for (int si = 0; si <= qt; ++si) {
    const int s0 = si * 64;
#pragma unroll
    for (int it = 0; it < 4; ++it) {
      const int li = it * 256 + tid;
      gload_lds16(kbase + (size_t)(s0 + rK + it * 16) * 128 + cKsw, &Ks[li * 8]);
      gload_lds16(vbase + (size_t)(rV + it * 32) * 1024 + s0 + cVsw, &Vts[li * 8]);
    }
    __syncthreads();

    // S = Q K^T
    float4v Sv[4];
#pragma unroll
    for (int j = 0; j < 4; ++j) Sv[j] = (float4v)0.0f;
#pragma unroll
    for (int ks = 0; ks < 4; ++ks) {
#pragma unroll
      for (int j = 0; j < 4; ++j) {
        short8 bk = *(const short8*)&Ks[(j * 16 + ml) * 128 + (((ks * 4 + q) ^ ml) * 8)];
        Sv[j] = __builtin_amdgcn_mfma_f32_16x16x32_bf16(aq[ks], bk, Sv[j], 0, 0, 0);
      }
    }

    // scale + causal mask + online softmax (rows: t = t0+w*16+q*4+rr)
    float P[4][4];
#pragma unroll
    for (int rr = 0; rr < 4; ++rr) {
      const int tg = t0 + w * 16 + q * 4 + rr;
      float vmax = -3e38f;
#pragma unroll
      for (int j = 0; j < 4; ++j) {
        const int sj = s0 + j * 16 + ml;
        float v = Sv[j][rr] * SCALE;
        if (sj > tg) v = -3.0e38f;
        P[j][rr] = v;
        vmax = fmaxf(vmax, v);
      }
      for (int off = 1; off < 16; off <<= 1) vmax = fmaxf(vmax, __shfl_xor(vmax, off));
      const float mnew = fmaxf(mrow[rr], vmax);
      const float alpha = __expf(mrow[rr] - mnew);
      mrow[rr] = mnew;
      lrow[rr] *= alpha;
#pragma unroll
      for (int ht = 0; ht < 8; ++ht) O[ht][rr] *= alpha;
      float rsum = 0.f;
#pragma unroll
      for (int j = 0; j < 4; ++j) {
        float e = __expf(P[j][rr] - mnew);
        P[j][rr] = e;
        rsum += e;
      }
      for (int off = 1; off < 16; off <<= 1) rsum += __shfl_xor(rsum, off);
      lrow[rr] += rsum;
    }

    // P: C-layout regs -> LDS [t][s] (padded stride 72)
#pragma unroll
    for (int rr = 0; rr < 4; ++rr)
#pragma unroll
      for (int j = 0; j < 4; ++j)
        Ps[(w * 16 + q * 4 + rr) * 72 + j * 16 + ml] = f2bf(P[j][rr]);

    // O += P V
#pragma unroll
    for (int ks = 0; ks < 2; ++ks) {
      short8 ap = *(const short8*)&Ps[(w * 16 + ml) * 72 + ks * 32 + q * 8];
#pragma unroll
      for (int ht = 0; ht < 8; ++ht) {
        short8 bv = *(const short8*)&Vts[(ht * 16 + ml) * 64 + (((ks * 4 + q) ^ (ml & 7)) * 8)];
        O[ht] = __builtin_amdgcn_mfma_f32_16x16x32_bf16(ap, bv, O[ht], 0, 0, 0);
      }
    }
    __syncthreads();
  }

  // epilogue: normalize, gate, store bf16 (M, N*H)
#pragma unroll
  for (int rr = 0; rr < 4; ++rr) {
    const int tg = t0 + w * 16 + q * 4 + rr;
    const size_t ob = ((size_t)(b * 1024 + tg) * 32 + n) * 128;
    const float inv = 1.0f / lrow[rr];
#pragma unroll
    for (int ht = 0; ht < 8; ++ht) {
      const int h = ht * 16 + ml;
      attn_out[ob + h] = f2bf(O[ht][rr] * inv * bf2f(sgate[ob + h]));
    }
  }
}

// ---------------------------------------------------------------------------
extern "C" void kernel_launch(void* const* d_in, const int* in_sizes, int n_in,
                              void* d_out, int out_size, void* d_ws, size_t ws_size,
                              hipStream_t stream) {
  (void)in_sizes; (void)n_in; (void)out_size; (void)ws_size;
  const float* x = (const float*)d_in[0];
  const int* pos = (const int*)d_in[1];
  const float* wq = (const float*)d_in[2];
  const float* wk = (const float*)d_in[3];
  const float* wv = (const float*)d_in[4];
  const float* wo = (const float*)d_in[5];
  const float* qnw = (const float*)d_in[6];
  const float* knw = (const float*)d_in[7];
  float* out = (float*)d_out;

  unsigned short* ws = (unsigned short*)d_ws;
  unsigned short* x_bf = ws;                         // 16777216
  unsigned short* wT = x_bf + 16777216;              // 41943040 (wq^T|wk^T|wv^T)
  unsigned short* woT = wT + 41943040;               // 16777216
  unsigned short* qkv = woT + 16777216;              // 41943040
  unsigned short* q_rot = qkv + 41943040;            // 16777216
  unsigned short* sgb = q_rot + 16777216;            // 16777216
  unsigned short* k_rot = sgb + 16777216;            // 4194304
  unsigned short* vtb = k_rot + 4194304;             // 4194304
  unsigned short* attn = wT;  // wT dead after GEMM1; reuse for attention out

  dim3 tb(32, 8);
  transpose_cvt<<<dim3(256, 128), tb, 0, stream>>>(wq, wT, 4096, 8192);
  transpose_cvt<<<dim3(32, 128), tb, 0, stream>>>(wk, wT + (size_t)8192 * 4096, 4096, 1024);
  transpose_cvt<<<dim3(32, 128), tb, 0, stream>>>(wv, wT + (size_t)9216 * 4096, 4096, 1024);
  transpose_cvt<<<dim3(128, 128), tb, 0, stream>>>(wo, woT, 4096, 4096);
  cvt_f32_bf16<<<16384, 256, 0, stream>>>(x, x_bf, 4194304);

  gemm_bt256<true><<<dim3(40, 16), 512, 0, stream>>>(x_bf, wT, (void*)qkv, 4096, 10240, 4096);
  postproc_kernel<<<40960, 256, 0, stream>>>(qkv, pos, qnw, knw, q_rot, sgb, k_rot);
  v_transpose<<<dim3(16, 2, 32), 256, 0, stream>>>(qkv, vtb);
  attn_kernel<<<2048, 256, 0, stream>>>(q_rot, k_rot, vtb, sgb, attn);
  gemm_bt256<false><<<dim3(16, 16), 512, 0, stream>>>(attn, woT, (void*)out, 4096, 4096, 4096);
}

// Round 2
// 1112.066 us; speedup vs baseline: 1.0216x; 1.0149x over previous
//
#include <hip/hip_runtime.h>
#include <cstdint>
#include <cstddef>

// ---------------------------------------------------------------------------
// Fused GQA attention block for MI355X (gfx950).
// B=4 T=1024 D=4096 N=32 Kh=8 G=4 H=128, rotary=80, theta=1e6, eps=1e-6.
// Pipeline: [transpose+cvt weights/x -> bf16] -> GEMM(qkv) -> norm/rope/gate
//           + V transpose -> flash attention (causal) -> GEMM(out proj).
// R3 change: fix the GEMM LDS swizzle. R2's chunk^=(row&3) left each 16-lane
// quarter-wave on only 16 of 32 banks (row stride 64B toggles bank-half with
// row&1, correlated with ml&3) -> 3.15e7 conflict cycles, MfmaUtil 35%.
// New swizzle chunk^=((row>>1)&3): 8-lane groups cover all 32 banks exactly
// once (16*(ml&1)+4*((ml>>1)&3) is a bijection onto the 8 4-bank groups).
// Applied both-sides (inverse-swizzled global source + swizzled ds_read).
// Pipeline structure (verified correct in R2, absmax unchanged): 256^2 tile,
// BK=32, 8 waves, 4-deep LDS ring, counted s_waitcnt vmcnt(8), per-phase
// {ds_read || global_load_lds -> barrier -> lgkmcnt(0) -> setprio(1)
//  16xMFMA setprio(0) -> barrier}.
// MFMA layouts (guide-verified, 16x16x32 bf16):
//   A-frag: A[m=lane&15][k=(lane>>4)*8+j]
//   B-frag: B[k=(lane>>4)*8+j][n=lane&15]  (from B^T rows)
//   C/D   : row=(lane>>4)*4+r, col=lane&15
// ---------------------------------------------------------------------------

typedef __attribute__((ext_vector_type(8))) short short8;
typedef __attribute__((ext_vector_type(4))) float float4v;

__device__ __forceinline__ unsigned short f2bf(float f) {
  unsigned u = __builtin_bit_cast(unsigned, f);
  u += 0x7fffu + ((u >> 16) & 1u);            // RNE
  return (unsigned short)(u >> 16);
}
__device__ __forceinline__ float bf2f(unsigned short h) {
  unsigned u = ((unsigned)h) << 16;
  return __builtin_bit_cast(float, u);
}

// async global->LDS, 16B per lane. LDS dest is wave-uniform base + lane*16.
__device__ __forceinline__ void gload_lds16(const void* g, void* l) {
  typedef const __attribute__((address_space(1))) void as1_cv;
  typedef __attribute__((address_space(3))) void as3_v;
  __builtin_amdgcn_global_load_lds((as1_cv*)g, (as3_v*)l, 16, 0, 0);
}

// ---------------------------------------------------------------------------
// Transpose + f32->bf16 convert: dst[c][r] = bf16(src[r][c]); src is (R, C).
// ---------------------------------------------------------------------------
__global__ __launch_bounds__(256) void transpose_cvt(
    const float* __restrict__ src, unsigned short* __restrict__ dst,
    int R, int C) {
  __shared__ float tile[32][33];
  const int c0 = blockIdx.x * 32, r0 = blockIdx.y * 32;
  for (int i = threadIdx.y; i < 32; i += 8)
    tile[i][threadIdx.x] = src[(size_t)(r0 + i) * C + c0 + threadIdx.x];
  __syncthreads();
  for (int i = threadIdx.y; i < 32; i += 8)
    dst[(size_t)(c0 + i) * R + r0 + threadIdx.x] = f2bf(tile[threadIdx.x][i]);
}

__global__ __launch_bounds__(256) void cvt_f32_bf16(
    const float* __restrict__ src, unsigned short* __restrict__ dst, int n4) {
  int i = blockIdx.x * blockDim.x + threadIdx.x;
  if (i >= n4) return;
  float4 f = ((const float4*)src)[i];
  ushort4 o;
  o.x = f2bf(f.x); o.y = f2bf(f.y); o.z = f2bf(f.z); o.w = f2bf(f.w);
  ((ushort4*)dst)[i] = o;
}

// bf16 64x64-tile transpose for V: qkv cols [9216+kh*128, +128) -> vt (b,kh,h,t).
// grid (16 t-tiles, 2 h-tiles, 32 b*kh), block 256.
__global__ __launch_bounds__(256) void v_transpose(
    const unsigned short* __restrict__ qkv, unsigned short* __restrict__ vtb) {
  __shared__ unsigned short tile[64][65];
  const int t0 = blockIdx.x * 64, h0 = blockIdx.y * 64;
  const int bk = blockIdx.z, b = bk >> 3, kh = bk & 7;
  const int tx = threadIdx.x & 63, ty = threadIdx.x >> 6;
  const unsigned short* src =
      qkv + (size_t)(b * 1024 + t0) * 10240 + 9216 + kh * 128 + h0;
  for (int i = ty; i < 64; i += 4)
    tile[i][tx] = src[(size_t)i * 10240 + tx];
  __syncthreads();
  unsigned short* dst = vtb + ((size_t)bk * 128 + h0) * 1024 + t0;
  for (int i = ty; i < 64; i += 4)
    dst[(size_t)i * 1024 + tx] = tile[tx][i];
}

// ---------------------------------------------------------------------------
// GEMM: C(M,N) = A(M,Kd) * BT(N,Kd)^T, bf16 in, f32 acc.
// 256x256 tile, BK=32, 512 threads = 8 waves (2x4), per-wave C = 128x64.
// LDS: 4-deep ring of (A 256x32 + B 256x32) bf16 = 128 KiB.
// Rows are 64 B = 4 chunks of 16 B; physical chunk c holds global chunk
// c ^ ((row >> 1) & 3)  (both-sides rule; bank-balanced at 8-lane granularity
// since 16*(row&1) + 4*chunk then covers all 8 4-bank groups bijectively).
// Pipeline: stage tile T+3 during tile T (1 A-half + 1 B-half issue per
// phase); boundary s_waitcnt vmcnt(8) before the last barrier of each tile.
// ---------------------------------------------------------------------------
template <bool BF16OUT>
__global__ __launch_bounds__(512, 2) void gemm_bt256(
    const unsigned short* __restrict__ A, const unsigned short* __restrict__ BT,
    void* __restrict__ Cv, int M, int N, int Kd) {
  __shared__ unsigned short As[4][256 * 32];
  __shared__ unsigned short Bs[4][256 * 32];

  const int tid = threadIdx.x;
  const int lane = tid & 63;
  const int wv = tid >> 6;
  const int wr = wv >> 2, wc = wv & 3;       // 2 x 4 wave grid
  const int m0 = blockIdx.y * 256, n0 = blockIdx.x * 256;
  const int ml = lane & 15, q = lane >> 4;

  // staging addressing: half s covers rows s*128..s*128+127 of the tile.
  // lane slot: row = tid>>2, phys chunk = tid&3; source chunk = phys^((row>>1)&3)
  const int sr = tid >> 2;
  const int pc = tid & 3;
  const int gc = (pc ^ ((sr >> 1) & 3)) * 8; // swizzled source col (ushorts)
  const unsigned short* gA0 = A + (size_t)(m0 + sr) * Kd + gc;
  const unsigned short* gB0 = BT + (size_t)(n0 + sr) * Kd + gc;
  const unsigned short* gA1 = gA0 + (size_t)128 * Kd;
  const unsigned short* gB1 = gB0 + (size_t)128 * Kd;
  const int lo0 = tid * 8;                   // LDS ushort offset, half 0
  const int lo1 = 4096 + tid * 8;            // half 1

  // fragment read addressing: frag row bases are %16==0, so
  // ((base+ml)>>1)&3 == (ml>>1)&3 — the XOR stays lane-local.
  const int rdc = (q ^ ((ml >> 1) & 3)) * 8; // swizzled chunk for ds_read
  const int aOff = (wr * 128 + ml) * 32 + rdc;
  const int bOff = (wc * 64 + ml) * 32 + rdc;

  float4v acc[8][4];
#pragma unroll
  for (int i = 0; i < 8; ++i)
#pragma unroll
    for (int j = 0; j < 4; ++j) acc[i][j] = (float4v)0.0f;

  const int NT = Kd >> 5;                    // K tiles of 32

  // prologue: stage tiles 0..2 (12 loads per wave); wait tile 0 (oldest 4).
#pragma unroll
  for (int t = 0; t < 3; ++t) {
    gload_lds16(gA0 + t * 32, &As[t][lo0]);
    gload_lds16(gA1 + t * 32, &As[t][lo1]);
    gload_lds16(gB0 + t * 32, &Bs[t][lo0]);
    gload_lds16(gB1 + t * 32, &Bs[t][lo1]);
  }
  asm volatile("s_waitcnt vmcnt(8)" ::: "memory");
  __builtin_amdgcn_s_barrier();

  for (int T = 0; T < NT; ++T) {
    const int buf = T & 3;
    const bool doStage = (T + 3 < NT);
    const int sb = (T + 3) & 3;
    const int gk = (T + 3) * 32;

    // ---- phase 0: B frags (all 4 n) + A frags 0..3 ----
    short8 bfr[4], af[4];
#pragma unroll
    for (int j = 0; j < 4; ++j)
      bfr[j] = *(const short8*)&Bs[buf][bOff + j * 512];
#pragma unroll
    for (int i = 0; i < 4; ++i)
      af[i] = *(const short8*)&As[buf][aOff + i * 512];
    if (doStage) {
      gload_lds16(gA0 + gk, &As[sb][lo0]);
      gload_lds16(gB0 + gk, &Bs[sb][lo0]);
    }
    __builtin_amdgcn_s_barrier();
    asm volatile("s_waitcnt lgkmcnt(0)" ::: "memory");
    __builtin_amdgcn_sched_barrier(0);
    __builtin_amdgcn_s_setprio(1);
#pragma unroll
    for (int i = 0; i < 4; ++i)
#pragma unroll
      for (int j = 0; j < 4; ++j)
        acc[i][j] = __builtin_amdgcn_mfma_f32_16x16x32_bf16(af[i], bfr[j], acc[i][j], 0, 0, 0);
    __builtin_amdgcn_s_setprio(0);
    __builtin_amdgcn_s_barrier();

    // ---- phase 1: A frags 4..7 (B frags reused) ----
#pragma unroll
    for (int i = 0; i < 4; ++i)
      af[i] = *(const short8*)&As[buf][aOff + 2048 + i * 512];
    if (doStage) {
      gload_lds16(gA1 + gk, &As[sb][lo1]);
      gload_lds16(gB1 + gk, &Bs[sb][lo1]);
    }
    __builtin_amdgcn_s_barrier();
    asm volatile("s_waitcnt lgkmcnt(0)" ::: "memory");
    __builtin_amdgcn_sched_barrier(0);
    __builtin_amdgcn_s_setprio(1);
#pragma unroll
    for (int i = 0; i < 4; ++i)
#pragma unroll
      for (int j = 0; j < 4; ++j)
        acc[4 + i][j] = __builtin_amdgcn_mfma_f32_16x16x32_bf16(af[i], bfr[j], acc[4 + i][j], 0, 0, 0);
    __builtin_amdgcn_s_setprio(0);
    // boundary wait BEFORE the closing barrier: tile T+1 must be resident;
    // tiles T+2 (4 loads) and T+3 (4 loads) may stay in flight.
    if (T + 3 < NT)
      asm volatile("s_waitcnt vmcnt(8)" ::: "memory");
    else if (T + 2 < NT)
      asm volatile("s_waitcnt vmcnt(4)" ::: "memory");
    else if (T + 1 < NT)
      asm volatile("s_waitcnt vmcnt(0)" ::: "memory");
    __builtin_amdgcn_s_barrier();
  }

  // epilogue
#pragma unroll
  for (int i = 0; i < 8; ++i) {
#pragma unroll
    for (int j = 0; j < 4; ++j) {
      const int grow = m0 + wr * 128 + i * 16 + q * 4;
      const int gcol = n0 + wc * 64 + j * 16 + ml;
#pragma unroll
      for (int r = 0; r < 4; ++r) {
        size_t idx = (size_t)(grow + r) * N + gcol;
        if constexpr (BF16OUT)
          ((unsigned short*)Cv)[idx] = f2bf(acc[i][j][r]);
        else
          ((float*)Cv)[idx] = acc[i][j][r];
      }
    }
  }
}

// ---------------------------------------------------------------------------
// Postprocess q/gate/k (V handled by v_transpose):
//   hs<32 : q head hs  -> rmsnorm, rope -> q_rot; gate -> sigmoid -> sgb
//   hs>=32: k head     -> rmsnorm, rope -> k_rot  (layout (b,kh,t,h))
// One wave per (row m, slot hs in 0..39). grid 40960, block 256.
// ---------------------------------------------------------------------------
__global__ __launch_bounds__(256) void postproc_kernel(
    const unsigned short* __restrict__ qkv, const int* __restrict__ positions,
    const float* __restrict__ qnw, const float* __restrict__ knw,
    unsigned short* __restrict__ q_rot, unsigned short* __restrict__ sgb,
    unsigned short* __restrict__ k_rot) {
  const int wave = threadIdx.x >> 6, lane = threadIdx.x & 63;
  const int gslot = blockIdx.x * 4 + wave;
  const int m = gslot / 40, hs = gslot % 40;
  const int b = m >> 10, t = m & 1023;

  const unsigned short* base = (hs < 32)
      ? qkv + (size_t)m * 10240 + hs * 256
      : qkv + (size_t)m * 10240 + 8192 + (hs - 32) * 128;

  float v1 = bf2f(base[lane]);        // h = lane
  float v2 = bf2f(base[64 + lane]);   // h = lane + 64

  // RMS norm over 128 (1+w applied before rope; rope mixes channels)
  float ss = v1 * v1 + v2 * v2;
  for (int off = 32; off > 0; off >>= 1) ss += __shfl_xor(ss, off);
  const float r = rsqrtf(ss * (1.0f / 128.0f) + 1e-6f);
  const float* nw = (hs < 32) ? qnw : knw;
  v1 *= r * (1.0f + nw[lane]);
  v2 *= r * (1.0f + nw[64 + lane]);

  // RoPE dims 0..79: pair (i, i+40). ln(1e6)/40 = 0.34538776...
  const float pos = (float)positions[m];
  const int i1 = (lane < 40) ? lane : lane - 40;
  const float ang1 = pos * expf(-0.3453877639491068f * (float)i1);
  const float s1 = sinf(ang1), c1 = cosf(ang1);
  const float ang2 = pos * expf(-0.3453877639491068f * (float)(lane + 24));
  const float s2 = sinf(ang2), c2 = cosf(ang2);

  const float shA1 = __shfl(v1, (lane + 40) & 63);
  const float shA2 = __shfl(v2, (lane + 40) & 63);
  const float shX = __shfl(v1, (lane + 24) & 63);
  const float pA = (lane < 24) ? shA1 : shA2;  // x[lane+40]
  const float o1 = (lane < 40) ? (v1 * c1 - pA * s1) : (v1 * c1 + shX * s1);
  const float o2 = (lane < 16) ? (v2 * c2 + shX * s2) : v2;

  if (hs < 32) {
    size_t qb = ((size_t)m * 32 + hs) * 128;
    q_rot[qb + lane] = f2bf(o1);
    q_rot[qb + 64 + lane] = f2bf(o2);
    float g1 = bf2f(base[128 + lane]), g2 = bf2f(base[192 + lane]);
    sgb[qb + lane] = f2bf(1.0f / (1.0f + expf(-g1)));
    sgb[qb + 64 + lane] = f2bf(1.0f / (1.0f + expf(-g2)));
  } else {
    const int kh = hs - 32;
    size_t kb = ((size_t)(b * 8 + kh) * 1024 + t) * 128;
    k_rot[kb + lane] = f2bf(o1);
    k_rot[kb + 64 + lane] = f2bf(o2);
  }
}

// ---------------------------------------------------------------------------
// Flash attention. Block = (b, n, 64-row Q tile). 4 waves x 16 q-rows.
// Ks/Vts XOR-swizzled; Ps padded to stride 72. LDS = 16K+16K+9K = 41KB.
// ---------------------------------------------------------------------------
__global__ __launch_bounds__(256) void attn_kernel(
    const unsigned short* __restrict__ q_rot, const unsigned short* __restrict__ k_rot,
    const unsigned short* __restrict__ vt, const unsigned short* __restrict__ sgate,
    unsigned short* __restrict__ attn_out) {
  __shared__ unsigned short Ks[64 * 128];   // 16 chunks/row, swizzle mask 15
  __shared__ unsigned short Vts[128 * 64];  // 8 chunks/row, swizzle mask 7
  __shared__ unsigned short Ps[64 * 72];    // padded, plain stores

  const int tid = threadIdx.x;
  const int lane = tid & 63, w = tid >> 6;
  const int qt = blockIdx.x & 15;
  const int n = (blockIdx.x >> 4) & 31;
  const int b = blockIdx.x >> 9;
  const int kh = n >> 2;
  const int t0 = qt * 64;
  const int ml = lane & 15, q = lane >> 4;
  const float SCALE = 0.08838834764831845f;  // H^-0.5

  short8 aq[4];
  {
    const unsigned short* qp =
        q_rot + (((size_t)(b * 1024 + t0 + w * 16 + ml)) * 32 + n) * 128 + q * 8;
#pragma unroll
    for (int ks = 0; ks < 4; ++ks) aq[ks] = *(const short8*)(qp + ks * 32);
  }

  float4v O[8];
#pragma unroll
  for (int i = 0; i < 8; ++i) O[i] = (float4v)0.0f;
  float mrow[4] = {-3e38f, -3e38f, -3e38f, -3e38f};
  float lrow[4] = {0.f, 0.f, 0.f, 0.f};

  const unsigned short* kbase = k_rot + (size_t)(b * 8 + kh) * 1024 * 128;
  const unsigned short* vbase = vt + (size_t)(b * 8 + kh) * 128 * 1024;
  const int rK = tid >> 4, cK = tid & 15;  // K stage: 64 rows x 16 chunks
  const int cKsw = (cK ^ rK) * 8;          // rK&15 == rK
  const int rV = tid >> 3, cV = tid & 7;   // V stage: 128 rows x 8 chunks
  const int cVsw = (cV ^ (rV & 7)) * 8;

  for (int si = 0; si <= qt; ++si) {
    const int s0 = si * 64;
#pragma unroll
    for (int it = 0; it < 4; ++it) {
      const int li = it * 256 + tid;
      gload_lds16(kbase + (size_t)(s0 + rK + it * 16) * 128 + cKsw, &Ks[li * 8]);
      gload_lds16(vbase + (size_t)(rV + it * 32) * 1024 + s0 + cVsw, &Vts[li * 8]);
    }
    __syncthreads();

    // S = Q K^T
    float4v Sv[4];
#pragma unroll
    for (int j = 0; j < 4; ++j) Sv[j] = (float4v)0.0f;
#pragma unroll
    for (int ks = 0; ks < 4; ++ks) {
#pragma unroll
      for (int j = 0; j < 4; ++j) {
        short8 bk = *(const short8*)&Ks[(j * 16 + ml) * 128 + (((ks * 4 + q) ^ ml) * 8)];
        Sv[j] = __builtin_amdgcn_mfma_f32_16x16x32_bf16(aq[ks], bk, Sv[j], 0, 0, 0);
      }
    }

    // scale + causal mask + online softmax (rows: t = t0+w*16+q*4+rr)
    float P[4][4];
#pragma unroll
    for (int rr = 0; rr < 4; ++rr) {
      const int tg = t0 + w * 16 + q * 4 + rr;
      float vmax = -3e38f;
#pragma unroll
      for (int j = 0; j < 4; ++j) {
        const int sj = s0 + j * 16 + ml;
        float v = Sv[j][rr] * SCALE;
        if (sj > tg) v = -3.0e38f;
        P[j][rr] = v;
        vmax = fmaxf(vmax, v);
      }
      for (int off = 1; off < 16; off <<= 1) vmax = fmaxf(vmax, __shfl_xor(vmax, off));
      const float mnew = fmaxf(mrow[rr], vmax);
      const float alpha = __expf(mrow[rr] - mnew);
      mrow[rr] = mnew;
      lrow[rr] *= alpha;
#pragma unroll
      for (int ht = 0; ht < 8; ++ht) O[ht][rr] *= alpha;
      float rsum = 0.f;
#pragma unroll
      for (int j = 0; j < 4; ++j) {
        float e = __expf(P[j][rr] - mnew);
        P[j][rr] = e;
        rsum += e;
      }
      for (int off = 1; off < 16; off <<= 1) rsum += __shfl_xor(rsum, off);
      lrow[rr] += rsum;
    }

    // P: C-layout regs -> LDS [t][s] (padded stride 72)
#pragma unroll
    for (int rr = 0; rr < 4; ++rr)
#pragma unroll
      for (int j = 0; j < 4; ++j)
        Ps[(w * 16 + q * 4 + rr) * 72 + j * 16 + ml] = f2bf(P[j][rr]);

    // O += P V
#pragma unroll
    for (int ks = 0; ks < 2; ++ks) {
      short8 ap = *(const short8*)&Ps[(w * 16 + ml) * 72 + ks * 32 + q * 8];
#pragma unroll
      for (int ht = 0; ht < 8; ++ht) {
        short8 bv = *(const short8*)&Vts[(ht * 16 + ml) * 64 + (((ks * 4 + q) ^ (ml & 7)) * 8)];
        O[ht] = __builtin_amdgcn_mfma_f32_16x16x32_bf16(ap, bv, O[ht], 0, 0, 0);
      }
    }
    __syncthreads();
  }

  // epilogue: normalize, gate, store bf16 (M, N*H)
#pragma unroll
  for (int rr = 0; rr < 4; ++rr) {
    const int tg = t0 + w * 16 + q * 4 + rr;
    const size_t ob = ((size_t)(b * 1024 + tg) * 32 + n) * 128;
    const float inv = 1.0f / lrow[rr];
#pragma unroll
    for (int ht = 0; ht < 8; ++ht) {
      const int h = ht * 16 + ml;
      attn_out[ob + h] = f2bf(O[ht][rr] * inv * bf2f(sgate[ob + h]));
    }
  }
}

// ---------------------------------------------------------------------------
extern "C" void kernel_launch(void* const* d_in, const int* in_sizes, int n_in,
                              void* d_out, int out_size, void* d_ws, size_t ws_size,
                              hipStream_t stream) {
  (void)in_sizes; (void)n_in; (void)out_size; (void)ws_size;
  const float* x = (const float*)d_in[0];
  const int* pos = (const int*)d_in[1];
  const float* wq = (const float*)d_in[2];
  const float* wk = (const float*)d_in[3];
  const float* wv = (const float*)d_in[4];
  const float* wo = (const float*)d_in[5];
  const float* qnw = (const float*)d_in[6];
  const float* knw = (const float*)d_in[7];
  float* out = (float*)d_out;

  unsigned short* ws = (unsigned short*)d_ws;
  unsigned short* x_bf = ws;                         // 16777216
  unsigned short* wT = x_bf + 16777216;              // 41943040 (wq^T|wk^T|wv^T)
  unsigned short* woT = wT + 41943040;               // 16777216
  unsigned short* qkv = woT + 16777216;              // 41943040
  unsigned short* q_rot = qkv + 41943040;            // 16777216
  unsigned short* sgb = q_rot + 16777216;            // 16777216
  unsigned short* k_rot = sgb + 16777216;            // 4194304
  unsigned short* vtb = k_rot + 4194304;             // 4194304
  unsigned short* attn = wT;  // wT dead after GEMM1; reuse for attention out

  dim3 tb(32, 8);
  transpose_cvt<<<dim3(256, 128), tb, 0, stream>>>(wq, wT, 4096, 8192);
  transpose_cvt<<<dim3(32, 128), tb, 0, stream>>>(wk, wT + (size_t)8192 * 4096, 4096, 1024);
  transpose_cvt<<<dim3(32, 128), tb, 0, stream>>>(wv, wT + (size_t)9216 * 4096, 4096, 1024);
  transpose_cvt<<<dim3(128, 128), tb, 0, stream>>>(wo, woT, 4096, 4096);
  cvt_f32_bf16<<<16384, 256, 0, stream>>>(x, x_bf, 4194304);

  gemm_bt256<true><<<dim3(40, 16), 512, 0, stream>>>(x_bf, wT, (void*)qkv, 4096, 10240, 4096);
  postproc_kernel<<<40960, 256, 0, stream>>>(qkv, pos, qnw, knw, q_rot, sgb, k_rot);
  v_transpose<<<dim3(16, 2, 32), 256, 0, stream>>>(qkv, vtb);
  attn_kernel<<<2048, 256, 0, stream>>>(q_rot, k_rot, vtb, sgb, attn);
  gemm_bt256<false><<<dim3(16, 16), 512, 0, stream>>>(attn, woT, (void*)out, 4096, 4096, 4096);
}

// Round 3
// 1092.926 us; speedup vs baseline: 1.0395x; 1.0175x over previous
//
#include <hip/hip_runtime.h>
#include <cstdint>
#include <cstddef>

// ---------------------------------------------------------------------------
// Fused GQA attention block for MI355X (gfx950).
// B=4 T=1024 D=4096 N=32 Kh=8 G=4 H=128, rotary=80, theta=1e6, eps=1e-6.
// Pipeline: [transpose+cvt weights/x -> bf16] -> GEMM(qkv) -> norm/rope/gate
//           + V transpose -> flash attention (causal) -> GEMM(out proj).
// R4 change: GEMM rebuilt around COUNTED lgkmcnt (the m201 lever R3 lacked).
// BK=64, 2-buffer LDS (128 KiB), 4 quadrant-phases per K-tile, ONE barrier
// per phase. q0 issues 16 ds_reads but waits lgkmcnt(4) -> B-hi frags land
// under the MFMA cluster; q2 issues A' reads then ALL 8 stage loads (reads
// never follow same-tile stage issues -> no conservative backend vmem wait
// on the read path); boundary vmcnt(0) acts on loads aged ~2 phases.
// Swizzle: R1-proven chunk^=(row&7) on 128-B rows (measured 0 conflicts).
// MFMA layouts (guide-verified, 16x16x32 bf16):
//   A-frag: A[m=lane&15][k=(lane>>4)*8+j]
//   B-frag: B[k=(lane>>4)*8+j][n=lane&15]  (from B^T rows)
//   C/D   : row=(lane>>4)*4+r, col=lane&15
// ---------------------------------------------------------------------------

typedef __attribute__((ext_vector_type(8))) short short8;
typedef __attribute__((ext_vector_type(4))) float float4v;

__device__ __forceinline__ unsigned short f2bf(float f) {
  unsigned u = __builtin_bit_cast(unsigned, f);
  u += 0x7fffu + ((u >> 16) & 1u);            // RNE
  return (unsigned short)(u >> 16);
}
__device__ __forceinline__ float bf2f(unsigned short h) {
  unsigned u = ((unsigned)h) << 16;
  return __builtin_bit_cast(float, u);
}

// async global->LDS, 16B per lane. LDS dest is wave-uniform base + lane*16.
__device__ __forceinline__ void gload_lds16(const void* g, void* l) {
  typedef const __attribute__((address_space(1))) void as1_cv;
  typedef __attribute__((address_space(3))) void as3_v;
  __builtin_amdgcn_global_load_lds((as1_cv*)g, (as3_v*)l, 16, 0, 0);
}

// ---------------------------------------------------------------------------
// Transpose + f32->bf16 convert: dst[c][r] = bf16(src[r][c]); src is (R, C).
// ---------------------------------------------------------------------------
__global__ __launch_bounds__(256) void transpose_cvt(
    const float* __restrict__ src, unsigned short* __restrict__ dst,
    int R, int C) {
  __shared__ float tile[32][33];
  const int c0 = blockIdx.x * 32, r0 = blockIdx.y * 32;
  for (int i = threadIdx.y; i < 32; i += 8)
    tile[i][threadIdx.x] = src[(size_t)(r0 + i) * C + c0 + threadIdx.x];
  __syncthreads();
  for (int i = threadIdx.y; i < 32; i += 8)
    dst[(size_t)(c0 + i) * R + r0 + threadIdx.x] = f2bf(tile[threadIdx.x][i]);
}

__global__ __launch_bounds__(256) void cvt_f32_bf16(
    const float* __restrict__ src, unsigned short* __restrict__ dst, int n4) {
  int i = blockIdx.x * blockDim.x + threadIdx.x;
  if (i >= n4) return;
  float4 f = ((const float4*)src)[i];
  ushort4 o;
  o.x = f2bf(f.x); o.y = f2bf(f.y); o.z = f2bf(f.z); o.w = f2bf(f.w);
  ((ushort4*)dst)[i] = o;
}

// bf16 64x64-tile transpose for V: qkv cols [9216+kh*128, +128) -> vt (b,kh,h,t).
// grid (16 t-tiles, 2 h-tiles, 32 b*kh), block 256.
__global__ __launch_bounds__(256) void v_transpose(
    const unsigned short* __restrict__ qkv, unsigned short* __restrict__ vtb) {
  __shared__ unsigned short tile[64][65];
  const int t0 = blockIdx.x * 64, h0 = blockIdx.y * 64;
  const int bk = blockIdx.z, b = bk >> 3, kh = bk & 7;
  const int tx = threadIdx.x & 63, ty = threadIdx.x >> 6;
  const unsigned short* src =
      qkv + (size_t)(b * 1024 + t0) * 10240 + 9216 + kh * 128 + h0;
  for (int i = ty; i < 64; i += 4)
    tile[i][tx] = src[(size_t)i * 10240 + tx];
  __syncthreads();
  unsigned short* dst = vtb + ((size_t)bk * 128 + h0) * 1024 + t0;
  for (int i = ty; i < 64; i += 4)
    dst[(size_t)i * 1024 + tx] = tile[tx][i];
}

// ---------------------------------------------------------------------------
// GEMM: C(M,N) = A(M,Kd) * BT(N,Kd)^T, bf16 in, f32 acc.
// 256x256 tile, BK=64, 512 threads = 8 waves (2x4), per-wave C = 128x64.
// LDS: 2 buffers x (A 256x64 + B 256x64) bf16 = 128 KiB.
// Rows are 128 B = 8 chunks of 16 B; physical chunk c holds global chunk
// c ^ (row & 7)  (both-sides rule; R1-verified 0 bank conflicts).
// Per K-tile: 4 quadrant phases (mh,nh) = (0,0),(0,1),(1,0),(1,1):
//   q0: 16 ds_reads (af mh0, bA, bB; order pinned), lgkmcnt(4), 16 MFMA, bar
//   q1: lgkmcnt(0) [bB, aged 1 phase], 16 MFMA, bar
//   q2: 8 ds_reads (af mh1) then 8 gload_lds (tile T+1), lgkmcnt(0),
//       16 MFMA, bar
//   q3: 16 MFMA (no waits), vmcnt(0) [stage loads aged ~2 phases], bar
// ---------------------------------------------------------------------------
template <bool BF16OUT>
__global__ __launch_bounds__(512, 2) void gemm_bt256(
    const unsigned short* __restrict__ A, const unsigned short* __restrict__ BT,
    void* __restrict__ Cv, int M, int N, int Kd) {
  __shared__ unsigned short As[2][16384];   // 256 rows x 64 (bf16)
  __shared__ unsigned short Bs[2][16384];

  const int tid = threadIdx.x;
  const int lane = tid & 63;
  const int wv = tid >> 6;
  const int wr = wv >> 2, wc = wv & 3;       // 2 x 4 wave grid
  const int m0 = blockIdx.y * 256, n0 = blockIdx.x * 256;
  const int ml = lane & 15, q = lane >> 4;

  // staging addressing: slot id = r*512+tid -> row = id>>3 (0..255 across
  // halves), phys chunk = tid&7; source chunk = phys ^ (row&7); row&7 is
  // invariant across rounds/halves (64,128 = 0 mod 8).
  const int srow = tid >> 3;                 // 0..63
  const int sgc = ((tid & 7) ^ (srow & 7)) * 8;
  const unsigned short* gA = A + (size_t)(m0 + srow) * Kd + sgc;
  const unsigned short* gB = BT + (size_t)(n0 + srow) * Kd + sgc;
  const int ldst = tid * 8;                  // ushort offset, round 0

  // fragment read addressing (frag row bases are %16==0 -> row&7 == ml&7)
  const int rch = (q ^ (ml & 7)) * 8;        // ks=0 chunk; ks=1 -> offset^32
  const int aBase = (wr * 128 + ml) * 64 + rch;
  const int bBase = (wc * 64 + ml) * 64 + rch;

  float4v acc[8][4];
#pragma unroll
  for (int i = 0; i < 8; ++i)
#pragma unroll
    for (int j = 0; j < 4; ++j) acc[i][j] = (float4v)0.0f;

  const int NT = Kd >> 6;                    // K tiles of 64

  // prologue: stage tile 0 into buf 0, drain, barrier.
#pragma unroll
  for (int h = 0; h < 4; ++h) {              // halves: A0,A1,B0,B1
    const unsigned short* g = (h < 2) ? gA : gB;
    const int hr = (h & 1) * 128;
    unsigned short* l = (h < 2) ? &As[0][(h & 1) * 8192] : &Bs[0][(h & 1) * 8192];
    gload_lds16(g + (size_t)hr * Kd, l + ldst);
    gload_lds16(g + (size_t)(hr + 64) * Kd, l + ldst + 4096);
  }
  asm volatile("s_waitcnt vmcnt(0)" ::: "memory");
  __builtin_amdgcn_s_barrier();

#pragma unroll 2
  for (int T = 0; T < NT; ++T) {
    const unsigned short* Ab = As[T & 1];
    const unsigned short* Bb = Bs[T & 1];
    const bool doStage = (T + 1 < NT);

    short8 af[8], ba[4], bb[4];
    // ---- q0: issue af(mh0)+bA (12 reads), then bB (4 reads, fly) ----
#pragma unroll
    for (int i = 0; i < 4; ++i) {
      af[i * 2]     = *(const short8*)&Ab[aBase + i * 1024];
      af[i * 2 + 1] = *(const short8*)&Ab[(aBase + i * 1024) ^ 32];
    }
#pragma unroll
    for (int j = 0; j < 2; ++j) {
      ba[j * 2]     = *(const short8*)&Bb[bBase + j * 1024];
      ba[j * 2 + 1] = *(const short8*)&Bb[(bBase + j * 1024) ^ 32];
    }
    __builtin_amdgcn_sched_barrier(0);       // pin: af+bA before bB
#pragma unroll
    for (int j = 0; j < 2; ++j) {
      bb[j * 2]     = *(const short8*)&Bb[bBase + 2048 + j * 1024];
      bb[j * 2 + 1] = *(const short8*)&Bb[(bBase + 2048 + j * 1024) ^ 32];
    }
    asm volatile("s_waitcnt lgkmcnt(4)" ::: "memory");  // af+bA forced
    __builtin_amdgcn_sched_barrier(0);
    __builtin_amdgcn_s_setprio(1);
#pragma unroll
    for (int i = 0; i < 4; ++i)
#pragma unroll
      for (int j = 0; j < 2; ++j) {
        acc[i][j] = __builtin_amdgcn_mfma_f32_16x16x32_bf16(af[i * 2], ba[j * 2], acc[i][j], 0, 0, 0);
        acc[i][j] = __builtin_amdgcn_mfma_f32_16x16x32_bf16(af[i * 2 + 1], ba[j * 2 + 1], acc[i][j], 0, 0, 0);
      }
    __builtin_amdgcn_s_setprio(0);
    __builtin_amdgcn_s_barrier();

    // ---- q1: bB forced (aged 1 phase) ----
    asm volatile("s_waitcnt lgkmcnt(0)" ::: "memory");
    __builtin_amdgcn_sched_barrier(0);
    __builtin_amdgcn_s_setprio(1);
#pragma unroll
    for (int i = 0; i < 4; ++i)
#pragma unroll
      for (int j = 0; j < 2; ++j) {
        acc[i][2 + j] = __builtin_amdgcn_mfma_f32_16x16x32_bf16(af[i * 2], bb[j * 2], acc[i][2 + j], 0, 0, 0);
        acc[i][2 + j] = __builtin_amdgcn_mfma_f32_16x16x32_bf16(af[i * 2 + 1], bb[j * 2 + 1], acc[i][2 + j], 0, 0, 0);
      }
    __builtin_amdgcn_s_setprio(0);
    __builtin_amdgcn_s_barrier();

    // ---- q2: af' (mh1) reads, THEN all 8 stage loads for tile T+1 ----
#pragma unroll
    for (int i = 0; i < 4; ++i) {
      af[i * 2]     = *(const short8*)&Ab[aBase + 4096 + i * 1024];
      af[i * 2 + 1] = *(const short8*)&Ab[(aBase + 4096 + i * 1024) ^ 32];
    }
    __builtin_amdgcn_sched_barrier(0);       // pin: reads before stage issue
    if (doStage) {
      const int sb = (T + 1) & 1;
      const size_t kk = (size_t)(T + 1) * 64;
#pragma unroll
      for (int h = 0; h < 4; ++h) {
        const unsigned short* g = (h < 2) ? gA : gB;
        const int hr = (h & 1) * 128;
        unsigned short* l = (h < 2) ? &As[sb][(h & 1) * 8192] : &Bs[sb][(h & 1) * 8192];
        gload_lds16(g + (size_t)hr * Kd + kk, l + ldst);
        gload_lds16(g + (size_t)(hr + 64) * Kd + kk, l + ldst + 4096);
      }
    }
    asm volatile("s_waitcnt lgkmcnt(0)" ::: "memory");  // af'
    __builtin_amdgcn_sched_barrier(0);
    __builtin_amdgcn_s_setprio(1);
#pragma unroll
    for (int i = 0; i < 4; ++i)
#pragma unroll
      for (int j = 0; j < 2; ++j) {
        acc[4 + i][j] = __builtin_amdgcn_mfma_f32_16x16x32_bf16(af[i * 2], ba[j * 2], acc[4 + i][j], 0, 0, 0);
        acc[4 + i][j] = __builtin_amdgcn_mfma_f32_16x16x32_bf16(af[i * 2 + 1], ba[j * 2 + 1], acc[4 + i][j], 0, 0, 0);
      }
    __builtin_amdgcn_s_setprio(0);
    __builtin_amdgcn_s_barrier();

    // ---- q3: pure MFMA (af', bB already forced); boundary ----
    __builtin_amdgcn_s_setprio(1);
#pragma unroll
    for (int i = 0; i < 4; ++i)
#pragma unroll
      for (int j = 0; j < 2; ++j) {
        acc[4 + i][2 + j] = __builtin_amdgcn_mfma_f32_16x16x32_bf16(af[i * 2], bb[j * 2], acc[4 + i][2 + j], 0, 0, 0);
        acc[4 + i][2 + j] = __builtin_amdgcn_mfma_f32_16x16x32_bf16(af[i * 2 + 1], bb[j * 2 + 1], acc[4 + i][2 + j], 0, 0, 0);
      }
    __builtin_amdgcn_s_setprio(0);
    if (doStage)
      asm volatile("s_waitcnt vmcnt(0)" ::: "memory");  // aged ~2 phases
    __builtin_amdgcn_s_barrier();
  }

  // epilogue (acc[i][j]: rows wr*128+i*16+q*4, cols wc*64+j*16+ml)
#pragma unroll
  for (int i = 0; i < 8; ++i) {
#pragma unroll
    for (int j = 0; j < 4; ++j) {
      const int grow = m0 + wr * 128 + i * 16 + q * 4;
      const int gcol = n0 + wc * 64 + j * 16 + ml;
#pragma unroll
      for (int r = 0; r < 4; ++r) {
        size_t idx = (size_t)(grow + r) * N + gcol;
        if constexpr (BF16OUT)
          ((unsigned short*)Cv)[idx] = f2bf(acc[i][j][r]);
        else
          ((float*)Cv)[idx] = acc[i][j][r];
      }
    }
  }
}

// ---------------------------------------------------------------------------
// Postprocess q/gate/k (V handled by v_transpose):
//   hs<32 : q head hs  -> rmsnorm, rope -> q_rot; gate -> sigmoid -> sgb
//   hs>=32: k head     -> rmsnorm, rope -> k_rot  (layout (b,kh,t,h))
// One wave per (row m, slot hs in 0..39). grid 40960, block 256.
// ---------------------------------------------------------------------------
__global__ __launch_bounds__(256) void postproc_kernel(
    const unsigned short* __restrict__ qkv, const int* __restrict__ positions,
    const float* __restrict__ qnw, const float* __restrict__ knw,
    unsigned short* __restrict__ q_rot, unsigned short* __restrict__ sgb,
    unsigned short* __restrict__ k_rot) {
  const int wave = threadIdx.x >> 6, lane = threadIdx.x & 63;
  const int gslot = blockIdx.x * 4 + wave;
  const int m = gslot / 40, hs = gslot % 40;
  const int b = m >> 10, t = m & 1023;

  const unsigned short* base = (hs < 32)
      ? qkv + (size_t)m * 10240 + hs * 256
      : qkv + (size_t)m * 10240 + 8192 + (hs - 32) * 128;

  float v1 = bf2f(base[lane]);        // h = lane
  float v2 = bf2f(base[64 + lane]);   // h = lane + 64

  // RMS norm over 128 (1+w applied before rope; rope mixes channels)
  float ss = v1 * v1 + v2 * v2;
  for (int off = 32; off > 0; off >>= 1) ss += __shfl_xor(ss, off);
  const float r = rsqrtf(ss * (1.0f / 128.0f) + 1e-6f);
  const float* nw = (hs < 32) ? qnw : knw;
  v1 *= r * (1.0f + nw[lane]);
  v2 *= r * (1.0f + nw[64 + lane]);

  // RoPE dims 0..79: pair (i, i+40). ln(1e6)/40 = 0.34538776...
  const float pos = (float)positions[m];
  const int i1 = (lane < 40) ? lane : lane - 40;
  const float ang1 = pos * expf(-0.3453877639491068f * (float)i1);
  const float s1 = sinf(ang1), c1 = cosf(ang1);
  const float ang2 = pos * expf(-0.3453877639491068f * (float)(lane + 24));
  const float s2 = sinf(ang2), c2 = cosf(ang2);

  const float shA1 = __shfl(v1, (lane + 40) & 63);
  const float shA2 = __shfl(v2, (lane + 40) & 63);
  const float shX = __shfl(v1, (lane + 24) & 63);
  const float pA = (lane < 24) ? shA1 : shA2;  // x[lane+40]
  const float o1 = (lane < 40) ? (v1 * c1 - pA * s1) : (v1 * c1 + shX * s1);
  const float o2 = (lane < 16) ? (v2 * c2 + shX * s2) : v2;

  if (hs < 32) {
    size_t qb = ((size_t)m * 32 + hs) * 128;
    q_rot[qb + lane] = f2bf(o1);
    q_rot[qb + 64 + lane] = f2bf(o2);
    float g1 = bf2f(base[128 + lane]), g2 = bf2f(base[192 + lane]);
    sgb[qb + lane] = f2bf(1.0f / (1.0f + expf(-g1)));
    sgb[qb + 64 + lane] = f2bf(1.0f / (1.0f + expf(-g2)));
  } else {
    const int kh = hs - 32;
    size_t kb = ((size_t)(b * 8 + kh) * 1024 + t) * 128;
    k_rot[kb + lane] = f2bf(o1);
    k_rot[kb + 64 + lane] = f2bf(o2);
  }
}

// ---------------------------------------------------------------------------
// Flash attention. Block = (b, n, 64-row Q tile). 4 waves x 16 q-rows.
// Ks/Vts XOR-swizzled; Ps padded to stride 72. LDS = 16K+16K+9K = 41KB.
// ---------------------------------------------------------------------------
__global__ __launch_bounds__(256) void attn_kernel(
    const unsigned short* __restrict__ q_rot, const unsigned short* __restrict__ k_rot,
    const unsigned short* __restrict__ vt, const unsigned short* __restrict__ sgate,
    unsigned short* __restrict__ attn_out) {
  __shared__ unsigned short Ks[64 * 128];   // 16 chunks/row, swizzle mask 15
  __shared__ unsigned short Vts[128 * 64];  // 8 chunks/row, swizzle mask 7
  __shared__ unsigned short Ps[64 * 72];    // padded, plain stores

  const int tid = threadIdx.x;
  const int lane = tid & 63, w = tid >> 6;
  const int qt = blockIdx.x & 15;
  const int n = (blockIdx.x >> 4) & 31;
  const int b = blockIdx.x >> 9;
  const int kh = n >> 2;
  const int t0 = qt * 64;
  const int ml = lane & 15, q = lane >> 4;
  const float SCALE = 0.08838834764831845f;  // H^-0.5

  short8 aq[4];
  {
    const unsigned short* qp =
        q_rot + (((size_t)(b * 1024 + t0 + w * 16 + ml)) * 32 + n) * 128 + q * 8;
#pragma unroll
    for (int ks = 0; ks < 4; ++ks) aq[ks] = *(const short8*)(qp + ks * 32);
  }

  float4v O[8];
#pragma unroll
  for (int i = 0; i < 8; ++i) O[i] = (float4v)0.0f;
  float mrow[4] = {-3e38f, -3e38f, -3e38f, -3e38f};
  float lrow[4] = {0.f, 0.f, 0.f, 0.f};

  const unsigned short* kbase = k_rot + (size_t)(b * 8 + kh) * 1024 * 128;
  const unsigned short* vbase = vt + (size_t)(b * 8 + kh) * 128 * 1024;
  const int rK = tid >> 4, cK = tid & 15;  // K stage: 64 rows x 16 chunks
  const int cKsw = (cK ^ rK) * 8;          // rK&15 == rK
  const int rV = tid >> 3, cV = tid & 7;   // V stage: 128 rows x 8 chunks
  const int cVsw = (cV ^ (rV & 7)) * 8;

  for (int si = 0; si <= qt; ++si) {
    const int s0 = si * 64;
#pragma unroll
    for (int it = 0; it < 4; ++it) {
      const int li = it * 256 + tid;
      gload_lds16(kbase + (size_t)(s0 + rK + it * 16) * 128 + cKsw, &Ks[li * 8]);
      gload_lds16(vbase + (size_t)(rV + it * 32) * 1024 + s0 + cVsw, &Vts[li * 8]);
    }
    __syncthreads();

    // S = Q K^T
    float4v Sv[4];
#pragma unroll
    for (int j = 0; j < 4; ++j) Sv[j] = (float4v)0.0f;
#pragma unroll
    for (int ks = 0; ks < 4; ++ks) {
#pragma unroll
      for (int j = 0; j < 4; ++j) {
        short8 bk = *(const short8*)&Ks[(j * 16 + ml) * 128 + (((ks * 4 + q) ^ ml) * 8)];
        Sv[j] = __builtin_amdgcn_mfma_f32_16x16x32_bf16(aq[ks], bk, Sv[j], 0, 0, 0);
      }
    }

    // scale + causal mask + online softmax (rows: t = t0+w*16+q*4+rr)
    float P[4][4];
#pragma unroll
    for (int rr = 0; rr < 4; ++rr) {
      const int tg = t0 + w * 16 + q * 4 + rr;
      float vmax = -3e38f;
#pragma unroll
      for (int j = 0; j < 4; ++j) {
        const int sj = s0 + j * 16 + ml;
        float v = Sv[j][rr] * SCALE;
        if (sj > tg) v = -3.0e38f;
        P[j][rr] = v;
        vmax = fmaxf(vmax, v);
      }
      for (int off = 1; off < 16; off <<= 1) vmax = fmaxf(vmax, __shfl_xor(vmax, off));
      const float mnew = fmaxf(mrow[rr], vmax);
      const float alpha = __expf(mrow[rr] - mnew);
      mrow[rr] = mnew;
      lrow[rr] *= alpha;
#pragma unroll
      for (int ht = 0; ht < 8; ++ht) O[ht][rr] *= alpha;
      float rsum = 0.f;
#pragma unroll
      for (int j = 0; j < 4; ++j) {
        float e = __expf(P[j][rr] - mnew);
        P[j][rr] = e;
        rsum += e;
      }
      for (int off = 1; off < 16; off <<= 1) rsum += __shfl_xor(rsum, off);
      lrow[rr] += rsum;
    }

    // P: C-layout regs -> LDS [t][s] (padded stride 72)
#pragma unroll
    for (int rr = 0; rr < 4; ++rr)
#pragma unroll
      for (int j = 0; j < 4; ++j)
        Ps[(w * 16 + q * 4 + rr) * 72 + j * 16 + ml] = f2bf(P[j][rr]);

    // O += P V
#pragma unroll
    for (int ks = 0; ks < 2; ++ks) {
      short8 ap = *(const short8*)&Ps[(w * 16 + ml) * 72 + ks * 32 + q * 8];
#pragma unroll
      for (int ht = 0; ht < 8; ++ht) {
        short8 bv = *(const short8*)&Vts[(ht * 16 + ml) * 64 + (((ks * 4 + q) ^ (ml & 7)) * 8)];
        O[ht] = __builtin_amdgcn_mfma_f32_16x16x32_bf16(ap, bv, O[ht], 0, 0, 0);
      }
    }
    __syncthreads();
  }

  // epilogue: normalize, gate, store bf16 (M, N*H)
#pragma unroll
  for (int rr = 0; rr < 4; ++rr) {
    const int tg = t0 + w * 16 + q * 4 + rr;
    const size_t ob = ((size_t)(b * 1024 + tg) * 32 + n) * 128;
    const float inv = 1.0f / lrow[rr];
#pragma unroll
    for (int ht = 0; ht < 8; ++ht) {
      const int h = ht * 16 + ml;
      attn_out[ob + h] = f2bf(O[ht][rr] * inv * bf2f(sgate[ob + h]));
    }
  }
}

// ---------------------------------------------------------------------------
extern "C" void kernel_launch(void* const* d_in, const int* in_sizes, int n_in,
                              void* d_out, int out_size, void* d_ws, size_t ws_size,
                              hipStream_t stream) {
  (void)in_sizes; (void)n_in; (void)out_size; (void)ws_size;
  const float* x = (const float*)d_in[0];
  const int* pos = (const int*)d_in[1];
  const float* wq = (const float*)d_in[2];
  const float* wk = (const float*)d_in[3];
  const float* wv = (const float*)d_in[4];
  const float* wo = (const float*)d_in[5];
  const float* qnw = (const float*)d_in[6];
  const float* knw = (const float*)d_in[7];
  float* out = (float*)d_out;

  unsigned short* ws = (unsigned short*)d_ws;
  unsigned short* x_bf = ws;                         // 16777216
  unsigned short* wT = x_bf + 16777216;              // 41943040 (wq^T|wk^T|wv^T)
  unsigned short* woT = wT + 41943040;               // 16777216
  unsigned short* qkv = woT + 16777216;              // 41943040
  unsigned short* q_rot = qkv + 41943040;            // 16777216
  unsigned short* sgb = q_rot + 16777216;            // 16777216
  unsigned short* k_rot = sgb + 16777216;            // 4194304
  unsigned short* vtb = k_rot + 4194304;             // 4194304
  unsigned short* attn = wT;  // wT dead after GEMM1; reuse for attention out

  dim3 tb(32, 8);
  transpose_cvt<<<dim3(256, 128), tb, 0, stream>>>(wq, wT, 4096, 8192);
  transpose_cvt<<<dim3(32, 128), tb, 0, stream>>>(wk, wT + (size_t)8192 * 4096, 4096, 1024);
  transpose_cvt<<<dim3(32, 128), tb, 0, stream>>>(wv, wT + (size_t)9216 * 4096, 4096, 1024);
  transpose_cvt<<<dim3(128, 128), tb, 0, stream>>>(wo, woT, 4096, 4096);
  cvt_f32_bf16<<<16384, 256, 0, stream>>>(x, x_bf, 4194304);

  gemm_bt256<true><<<dim3(40, 16), 512, 0, stream>>>(x_bf, wT, (void*)qkv, 4096, 10240, 4096);
  postproc_kernel<<<40960, 256, 0, stream>>>(qkv, pos, qnw, knw, q_rot, sgb, k_rot);
  v_transpose<<<dim3(16, 2, 32), 256, 0, stream>>>(qkv, vtb);
  attn_kernel<<<2048, 256, 0, stream>>>(q_rot, k_rot, vtb, sgb, attn);
  gemm_bt256<false><<<dim3(16, 16), 512, 0, stream>>>(attn, woT, (void*)out, 4096, 4096, 4096);
}